// Round 1
// baseline (184.120 us; speedup 1.0000x reference)
//
#include <hip/hip_runtime.h>

#define SS 2048
#define NH 16
#define NKV 4
#define HD 64

typedef __bf16 bf16;
typedef __bf16 bf16x4 __attribute__((ext_vector_type(4)));
typedef __bf16 bf16x8 __attribute__((ext_vector_type(8)));
typedef float f32x4 __attribute__((ext_vector_type(4)));

// softmax scale folded into Q at the QKV epilogue: (1/sqrt(64)) * log2(e)
#define SM_SCALE 0.18033688011f

__device__ __forceinline__ void gl_lds16(const bf16* g, bf16* l) {
    __builtin_amdgcn_global_load_lds((const __attribute__((address_space(1))) void*)g,
                                     (__attribute__((address_space(3))) void*)l, 16, 0, 0);
}

// ---------------- prep: transpose/convert weights only (x conversion fused into QKV GEMM) ----
// blocks 0..255: Wq (16x16 64-tiles), 256..319: Wk, 320..383: Wv, 384..639: Wo.
__global__ __launch_bounds__(256) void prep_kernel(
    const float* __restrict__ Wq, const float* __restrict__ Wk,
    const float* __restrict__ Wv, const float* __restrict__ Wo,
    bf16* __restrict__ wqkv_t, bf16* __restrict__ wo_t)
{
    const int blk = blockIdx.x;
    const int tid = threadIdx.x;
    const float* W; bf16* Wt; int N, n0, k0;
    if (blk < 256)      { W = Wq; Wt = wqkv_t;                       N = 1024; n0 = (blk & 15) * 64;         k0 = (blk >> 4) * 64; }
    else if (blk < 320) { W = Wk; Wt = wqkv_t + (size_t)1024 * 1024; N = 256;  n0 = ((blk - 256) & 3) * 64;  k0 = ((blk - 256) >> 2) * 64; }
    else if (blk < 384) { W = Wv; Wt = wqkv_t + (size_t)1280 * 1024; N = 256;  n0 = ((blk - 320) & 3) * 64;  k0 = ((blk - 320) >> 2) * 64; }
    else                { W = Wo; Wt = wo_t;                         N = 1024; n0 = ((blk - 384) & 15) * 64; k0 = ((blk - 384) >> 4) * 64; }

    __shared__ float Ts[64][65];
    const int c = tid & 63, rr = tid >> 6;
    #pragma unroll
    for (int i = 0; i < 16; ++i) {
        const int kk = i * 4 + rr;
        Ts[kk][c] = W[(size_t)(k0 + kk) * N + n0 + c];
    }
    __syncthreads();
    #pragma unroll
    for (int i = 0; i < 16; ++i) {
        const int nn = i * 4 + rr;
        Wt[(size_t)(n0 + nn) * 1024 + k0 + c] = (bf16)Ts[c][nn];
    }
}

// ---------------- bf16 MFMA GEMM, 256 threads (4 waves), 128x128 tile, BK=64 ----------------
// Bt(N,K) rm bf16 via global_load_lds. Wave grid 2x2: wave tile 64x64 -> 32 MFMA/wave/K-step
// (m93/m97 structure: acc[4][4], measured 912 TF at 4096^3 on this exact shape).
// Unpadded LDS with chunk-XOR swizzle: phys chunk p of row r holds logical chunk p^(r&7);
// frag reads use ((t*4+g)^(li&7)) -> 2-way conflicts only (free, m136).
// EPI=0: A bf16 (gl_lds), C fp32 plain.
// EPI=2: A fp32 (coalesced vector load + cvt + SWIZZLED ds_write), fused RoPE+QKV split, Q pre-scaled.
template<int EPI>
__global__ __launch_bounds__(256) void gemm_bt_kernel(
    const bf16* __restrict__ A, const float* __restrict__ Af,
    const bf16* __restrict__ Bt, float* __restrict__ C,
    const float* __restrict__ cosp, const float* __restrict__ sinp,
    bf16* __restrict__ qo, bf16* __restrict__ ko, bf16* __restrict__ vto,
    int M, int N, int K)
{
    __shared__ bf16 As[128 * 64];   // 16 KB
    __shared__ bf16 Bs[128 * 64];   // 16 KB
    const int m0 = blockIdx.x * 128, n0 = blockIdx.y * 128;
    const int tid = threadIdx.x;
    const int w = tid >> 6, lane = tid & 63, g = lane >> 4, li = lane & 15;
    const int wm = w >> 1, wn = w & 1;      // wave tile: rows wm*64+mi*16 (mi<4), cols wn*64+ni*16 (ni<4)

    f32x4 acc[4][4];
    const f32x4 z = {0.f, 0.f, 0.f, 0.f};
    #pragma unroll
    for (int i = 0; i < 4; ++i)
        #pragma unroll
        for (int j = 0; j < 4; ++j) acc[i][j] = z;

    // staging sweep = 256 thr x 16B = 32 rows x 64 elems; wave w covers rows w*8..w*8+7.
    const int srow = tid >> 3;                          // 0..31 (row within sweep)
    const int schunk = ((tid & 7) ^ (srow & 7)) * 8;    // swizzled 8-elem chunk (phys for ds_write, logical for gl_lds)
    const bf16* pB[4];
    const bf16* pA[4];
    bf16* lB[4];
    bf16* lA[4];
    #pragma unroll
    for (int s = 0; s < 4; ++s) {
        pB[s] = Bt + (size_t)(n0 + s * 32 + srow) * K + schunk;
        lB[s] = Bs + s * 2048 + (size_t)w * 512;
        if (EPI == 0) pA[s] = A + (size_t)(m0 + s * 32 + srow) * K + schunk;
        lA[s] = As + s * 2048 + (size_t)w * 512;
    }

    for (int kk = 0; kk < K; kk += 64) {
        __syncthreads();
        if (EPI == 0) {
            #pragma unroll
            for (int s = 0; s < 4; ++s) gl_lds16(pA[s] + kk, lA[s]);
        } else {
            // A fp32 -> bf16 conversion fused into staging.
            // Load UNSWIZZLED lane chunk (tid&7) from global (coalesced), store at
            // SWIZZLED phys chunk schunk: phys p then holds logical p^(row&7).
            #pragma unroll
            for (int s = 0; s < 4; ++s) {
                const float* src = Af + (size_t)(m0 + s * 32 + srow) * K + kk + (tid & 7) * 8;
                const float4 v0 = *(const float4*)src;
                const float4 v1 = *(const float4*)(src + 4);
                bf16x8 t8;
                t8[0] = (bf16)v0.x; t8[1] = (bf16)v0.y; t8[2] = (bf16)v0.z; t8[3] = (bf16)v0.w;
                t8[4] = (bf16)v1.x; t8[5] = (bf16)v1.y; t8[6] = (bf16)v1.z; t8[7] = (bf16)v1.w;
                *(bf16x8*)&As[(s * 32 + srow) * 64 + schunk] = t8;
            }
        }
        #pragma unroll
        for (int s = 0; s < 4; ++s) gl_lds16(pB[s] + kk, lB[s]);
        __syncthreads();
        #pragma unroll
        for (int t = 0; t < 2; ++t) {
            const int phys = ((t * 4 + g) ^ (li & 7)) * 8;
            bf16x8 af[4], bfr[4];
            #pragma unroll
            for (int mi = 0; mi < 4; ++mi) af[mi] = *(const bf16x8*)&As[(wm * 64 + mi * 16 + li) * 64 + phys];
            #pragma unroll
            for (int ni = 0; ni < 4; ++ni) bfr[ni] = *(const bf16x8*)&Bs[(wn * 64 + ni * 16 + li) * 64 + phys];
            #pragma unroll
            for (int mi = 0; mi < 4; ++mi)
                #pragma unroll
                for (int ni = 0; ni < 4; ++ni)
                    acc[mi][ni] = __builtin_amdgcn_mfma_f32_16x16x32_bf16(af[mi], bfr[ni], acc[mi][ni], 0, 0, 0);
        }
    }

    const int row0 = m0 + wm * 64, col0 = n0 + wn * 64;
    if (EPI == 0) {
        #pragma unroll
        for (int mi = 0; mi < 4; ++mi)
            #pragma unroll
            for (int ni = 0; ni < 4; ++ni)
                #pragma unroll
                for (int r = 0; r < 4; ++r)
                    C[(size_t)(row0 + mi * 16 + g * 4 + r) * N + col0 + ni * 16 + li] = acc[mi][ni][r];
    } else {
        // fused RoPE + split. cols: [0,1024) q (pre-scaled), [1024,1280) k, [1280,1536) v.
        // rotate_half partner of col is col^32 == acc[mi][ni^2][r] (same wave, in-register).
        #pragma unroll
        for (int ni = 0; ni < 4; ++ni) {
            const int col = col0 + ni * 16 + li;
            const int d = col & 63;
            #pragma unroll
            for (int mi = 0; mi < 4; ++mi) {
                #pragma unroll
                for (int r = 0; r < 4; ++r) {
                    const int row = row0 + mi * 16 + g * 4 + r;
                    const int bb = row >> 11, s = row & 2047;
                    float val = acc[mi][ni][r];
                    if (col < 1280) {
                        const float pairv = acc[mi][ni ^ 2][r];
                        const float rot = (d < 32) ? -pairv : pairv;
                        val = val * cosp[s * 64 + d] + rot * sinp[s * 64 + d];
                    }
                    if (col < 1024) {
                        const int hh = col >> 6;
                        qo[(((size_t)bb * NH + hh) * SS + s) * HD + d] = (bf16)(val * SM_SCALE);
                    } else if (col < 1280) {
                        const int kh = (col - 1024) >> 6;
                        ko[(((size_t)bb * NKV + kh) * SS + s) * HD + d] = (bf16)val;
                    } else {
                        const int kh = (col - 1280) >> 6;
                        vto[(((size_t)bb * NKV + kh) * HD + d) * SS + s] = (bf16)val;  // V^T: [d][s]
                    }
                }
            }
        }
    }
}

// ---------------- Flash attention v8: swapped QK^T -> packed P writes ----------------
// 1024 blocks x 256 thr. qt = 31 - blk/32 (heaviest first), (b,h) = blk&31.
// Ks/Vt unpadded + chunk-XOR swizzle, staged via global_load_lds (8 calls / 128 keys).
// QK^T computed SWAPPED: s = mfma(kf, qf) so lane (li,g) holds S[key=nt*16+g*4+r][q=li]
// -> 4-consecutive-key runs of the lane's own q-row. exp2'd runs pack to bf16x4 and store
// with ONE ds_write_b64 per nt (was 16 scalar ds_write_b16 per sub-tile).
// Ps per wave = [q=16][key=64] bf16, 8B-chunk XOR swizzle: phys_chunk = c ^ ((li&7)<<1).
// Even mask keeps b128 pf reads 16B-contiguous and in-order; writes and reads both sit at
// the LDS bank floor (balanced accesses).
__global__ __launch_bounds__(256) void flash_kernel(const bf16* __restrict__ q, const bf16* __restrict__ k,
                                                    const bf16* __restrict__ vt, bf16* __restrict__ o)
{
    __shared__ bf16 Ks[128 * 64];    // 16 KB: 128 keys x 64 d, swizzled
    __shared__ bf16 Vt[64 * 128];    // 16 KB: 64 d x 128 keys, swizzled
    __shared__ bf16 Ps[4][16 * 64];  //  8 KB: per-wave P [q][key], chunk-swizzled

    const int blk = blockIdx.x;
    const int qt = 31 - (blk >> 5);          // heavy blocks dispatched first
    const int h = blk & 15;
    const int b = (blk >> 4) & 1;
    const int kvh = h >> 2;
    const int tid = threadIdx.x;
    const int w = tid >> 6, lane = tid & 63, g = lane >> 4, li = lane & 15;

    const bf16* qh = q + ((size_t)b * NH + h) * SS * HD;
    const bf16* kh = k + ((size_t)b * NKV + kvh) * SS * HD;
    const bf16* vh = vt + ((size_t)b * NKV + kvh) * (size_t)HD * SS;

    bf16x8 ones;
    #pragma unroll
    for (int j = 0; j < 8; ++j) ones[j] = (bf16)1.0f;
    const f32x4 z = {0.f, 0.f, 0.f, 0.f};

    // Q fragments straight from global (row=li, k=g*8+j); Q pre-scaled.
    const bf16* qrow = qh + (size_t)(qt * 64 + w * 16 + li) * HD;
    bf16x8 qf[2];
    qf[0] = *(const bf16x8*)(qrow + g * 8);
    qf[1] = *(const bf16x8*)(qrow + 32 + g * 8);

    // staging lane maps (swizzled, wave-uniform LDS dests)
    const int ksrow = tid >> 3;                              // K: 0..31 within 32-row sweep
    const int kchunk = ((tid & 7) ^ (ksrow & 7)) * 8;
    const int vsrow = tid >> 4;                              // Vt: 0..15 within 16-row sweep
    const int vchunk = (((tid & 15) ^ (vsrow & 7)) & 15) * 8;
    bf16* lK = Ks + (size_t)w * 512;
    bf16* lV = Vt + (size_t)w * 512;

    const int xm = (li & 7) << 1;   // even Ps chunk-XOR mask (row-dependent, read==write)

    f32x4 o_acc[4], l_acc;
    #pragma unroll
    for (int nt = 0; nt < 4; ++nt) o_acc[nt] = z;
    l_acc = z;

    for (int kt0 = 0; kt0 <= qt; kt0 += 2) {
        __syncthreads();
        {   // stage 128 keys of K (4 sweeps x 32 rows) and V^T (4 sweeps x 16 d-rows)
            #pragma unroll
            for (int s = 0; s < 4; ++s)
                gl_lds16(kh + (size_t)(kt0 * 64 + s * 32 + ksrow) * HD + kchunk, lK + s * 2048);
            #pragma unroll
            for (int s = 0; s < 4; ++s)
                gl_lds16(vh + (size_t)(s * 16 + vsrow) * SS + kt0 * 64 + vchunk, lV + s * 2048);
        }
        __syncthreads();

        #pragma unroll
        for (int sub = 0; sub < 2; ++sub) {
            const int kt = kt0 + sub;
            if (kt > qt) break;

            // S^T-fragment = K @ Q^T (swapped): lane (li,g) holds S[key=nt*16+g*4+r][q=li]
            f32x4 s_acc[4];
            #pragma unroll
            for (int nt = 0; nt < 4; ++nt) s_acc[nt] = z;
            #pragma unroll
            for (int t = 0; t < 2; ++t)
                #pragma unroll
                for (int nt = 0; nt < 4; ++nt) {
                    const bf16x8 kf = *(const bf16x8*)&Ks[(sub * 64 + nt * 16 + li) * 64 + (((t * 4 + g) ^ (li & 7)) * 8)];
                    s_acc[nt] = __builtin_amdgcn_mfma_f32_16x16x32_bf16(kf, qf[t], s_acc[nt], 0, 0, 0);
                }

            // exp2 + packed P -> LDS (bf16x4 per nt). Diag tile masked separately.
            if (kt == qt) {
                const int qrow_in = w * 16 + li;   // q within the 64-row q-tile
                #pragma unroll
                for (int nt = 0; nt < 4; ++nt) {
                    bf16x4 p4;
                    #pragma unroll
                    for (int r = 0; r < 4; ++r) {
                        float sv = s_acc[nt][r];
                        if (nt * 16 + g * 4 + r > qrow_in) sv = -1e30f;
                        p4[r] = (bf16)exp2f(sv);
                    }
                    *(bf16x4*)&Ps[w][li * 64 + (((nt * 4 + g) ^ xm) * 4)] = p4;
                }
            } else {
                #pragma unroll
                for (int nt = 0; nt < 4; ++nt) {
                    bf16x4 p4;
                    #pragma unroll
                    for (int r = 0; r < 4; ++r) p4[r] = (bf16)exp2f(s_acc[nt][r]);
                    *(bf16x4*)&Ps[w][li * 64 + (((nt * 4 + g) ^ xm) * 4)] = p4;
                }
            }
            // same-wave LDS round-trip (rows are the lane's own q=li); no barrier needed

            // O += P @ V ; l += P @ 1 (rowsum via ones-MFMA)
            #pragma unroll
            for (int t = 0; t < 2; ++t) {
                const bf16x8 pf = *(const bf16x8*)&Ps[w][li * 64 + (((t * 8 + g * 2) ^ xm) * 4)];
                l_acc = __builtin_amdgcn_mfma_f32_16x16x32_bf16(pf, ones, l_acc, 0, 0, 0);
                #pragma unroll
                for (int nt = 0; nt < 4; ++nt) {
                    const bf16x8 vf = *(const bf16x8*)&Vt[(nt * 16 + li) * 128 + (((sub * 8 + t * 4 + g) ^ (li & 7)) * 8)];
                    o_acc[nt] = __builtin_amdgcn_mfma_f32_16x16x32_bf16(pf, vf, o_acc[nt], 0, 0, 0);
                }
            }
        }
    }

    // epilogue: O / l -> (b, s, h, d) bf16
    #pragma unroll
    for (int r = 0; r < 4; ++r) {
        const float inv = 1.f / l_acc[r];
        const int s = qt * 64 + w * 16 + g * 4 + r;
        bf16* orow = o + (((size_t)b * SS + s) * NH + h) * HD;
        #pragma unroll
        for (int nt = 0; nt < 4; ++nt) orow[nt * 16 + li] = (bf16)(o_acc[nt][r] * inv);
    }
}

extern "C" void kernel_launch(void* const* d_in, const int* in_sizes, int n_in,
                              void* d_out, int out_size, void* d_ws, size_t ws_size,
                              hipStream_t stream) {
    const float* x     = (const float*)d_in[0];
    const float* cos_t = (const float*)d_in[1];
    const float* sin_t = (const float*)d_in[2];
    const float* Wq    = (const float*)d_in[3];
    const float* Wk    = (const float*)d_in[4];
    const float* Wv    = (const float*)d_in[5];
    const float* Wo    = (const float*)d_in[6];
    float* out = (float*)d_out;

    char* wsb = (char*)d_ws;
    bf16* o_b    = (bf16*)(wsb);                 //  8,388,608 B (attention output)
    bf16* wqkv_t = (bf16*)(wsb + 8388608);       //  3,145,728 B (1536 x 1024)
    bf16* wo_t   = (bf16*)(wsb + 11534336);      //  2,097,152 B (1024 x 1024)
    bf16* q_b    = (bf16*)(wsb + 13631488);      //  8,388,608 B
    bf16* k_b    = (bf16*)(wsb + 22020096);      //  2,097,152 B
    bf16* vt_b   = (bf16*)(wsb + 24117248);      //  2,097,152 B -> total 26,214,400 B

    prep_kernel<<<640, 256, 0, stream>>>(Wq, Wk, Wv, Wo, wqkv_t, wo_t);

    // QKV GEMM: A = x (fp32, converted in-staging) with fused RoPE + split, 128x128 tiles
    gemm_bt_kernel<2><<<dim3(32, 12), 256, 0, stream>>>(nullptr, x, wqkv_t, nullptr, cos_t, sin_t,
                                                        q_b, k_b, vt_b, 4096, 1536, 1024);
    flash_kernel<<<1024, 256, 0, stream>>>(q_b, k_b, vt_b, o_b);
    gemm_bt_kernel<0><<<dim3(32, 8), 256, 0, stream>>>(o_b, nullptr, wo_t, out, nullptr, nullptr,
                                                       nullptr, nullptr, nullptr, 4096, 1024, 1024);
}

// Round 2
// 166.851 us; speedup vs baseline: 1.1035x; 1.1035x over previous
//
#include <hip/hip_runtime.h>

#define SS 2048
#define NH 16
#define NKV 4
#define HD 64

typedef __bf16 bf16;
typedef __bf16 bf16x4 __attribute__((ext_vector_type(4)));
typedef __bf16 bf16x8 __attribute__((ext_vector_type(8)));
typedef float f32x4 __attribute__((ext_vector_type(4)));

// softmax scale folded into Q at the QKV epilogue: (1/sqrt(64)) * log2(e)
#define SM_SCALE 0.18033688011f

__device__ __forceinline__ void gl_lds16(const bf16* g, bf16* l) {
    __builtin_amdgcn_global_load_lds((const __attribute__((address_space(1))) void*)g,
                                     (__attribute__((address_space(3))) void*)l, 16, 0, 0);
}

// ---------------- prep: transpose/convert weights only (x conversion fused into QKV GEMM) ----
// blocks 0..255: Wq (16x16 64-tiles), 256..319: Wk, 320..383: Wv, 384..639: Wo.
__global__ __launch_bounds__(256) void prep_kernel(
    const float* __restrict__ Wq, const float* __restrict__ Wk,
    const float* __restrict__ Wv, const float* __restrict__ Wo,
    bf16* __restrict__ wqkv_t, bf16* __restrict__ wo_t)
{
    const int blk = blockIdx.x;
    const int tid = threadIdx.x;
    const float* W; bf16* Wt; int N, n0, k0;
    if (blk < 256)      { W = Wq; Wt = wqkv_t;                       N = 1024; n0 = (blk & 15) * 64;         k0 = (blk >> 4) * 64; }
    else if (blk < 320) { W = Wk; Wt = wqkv_t + (size_t)1024 * 1024; N = 256;  n0 = ((blk - 256) & 3) * 64;  k0 = ((blk - 256) >> 2) * 64; }
    else if (blk < 384) { W = Wv; Wt = wqkv_t + (size_t)1280 * 1024; N = 256;  n0 = ((blk - 320) & 3) * 64;  k0 = ((blk - 320) >> 2) * 64; }
    else                { W = Wo; Wt = wo_t;                         N = 1024; n0 = ((blk - 384) & 15) * 64; k0 = ((blk - 384) >> 4) * 64; }

    __shared__ float Ts[64][65];
    const int c = tid & 63, rr = tid >> 6;
    #pragma unroll
    for (int i = 0; i < 16; ++i) {
        const int kk = i * 4 + rr;
        Ts[kk][c] = W[(size_t)(k0 + kk) * N + n0 + c];
    }
    __syncthreads();
    #pragma unroll
    for (int i = 0; i < 16; ++i) {
        const int nn = i * 4 + rr;
        Wt[(size_t)(n0 + nn) * 1024 + k0 + c] = (bf16)Ts[c][nn];
    }
}

// ---------------- bf16 MFMA GEMM, 256 threads (4 waves), 64x128 tile, BK=64 ----------------
// Round-2 structure: DOUBLE-BUFFERED LDS, 2-phase pipeline (T3 minimum recipe):
//   prologue: stage(buf0); barrier;
//   iter t:   stage(buf^1, t+1) issued FIRST; compute(buf); ONE barrier.
// Staging latency hides under the MFMA phase instead of being drained cold at a
// second barrier (round-0/1 structure had 2 barriers/K-step with staging fully exposed).
// 64x128 tile (not 128x128): grids 768/512 blocks keep ~3 blocks/CU resident —
// round-1 counters showed 128^2 collapses occupancy to ~1 block/CU (13.5%) at these shapes.
// Unpadded LDS with chunk-XOR swizzle: phys chunk p of row r holds logical chunk p^(r&7);
// frag reads use ((t*4+g)^(li&7)) -> 2-way conflicts only (free, m136).
// EPI=0: A bf16 (gl_lds), C fp32 plain.
// EPI=2: A fp32, T14 split staging: float4 loads BEFORE compute, cvt+ds_write AFTER;
//        fused RoPE+QKV split epilogue, Q pre-scaled.
template<int EPI>
__global__ __launch_bounds__(256) void gemm_bt_kernel(
    const bf16* __restrict__ A, const float* __restrict__ Af,
    const bf16* __restrict__ Bt, float* __restrict__ C,
    const float* __restrict__ cosp, const float* __restrict__ sinp,
    bf16* __restrict__ qo, bf16* __restrict__ ko, bf16* __restrict__ vto,
    int M, int N, int K)
{
    __shared__ bf16 As[2][64 * 64];    // 2 x  8 KB
    __shared__ bf16 Bs[2][128 * 64];   // 2 x 16 KB -> 48 KB total, 3 blocks/CU
    const int m0 = blockIdx.x * 64, n0 = blockIdx.y * 128;
    const int tid = threadIdx.x;
    const int w = tid >> 6, lane = tid & 63, g = lane >> 4, li = lane & 15;
    const int wm = w >> 1, wn = w & 1;      // wave tile: rows wm*32+mi*16 (mi<2), cols wn*64+ni*16 (ni<4)

    f32x4 acc[2][4];
    const f32x4 z = {0.f, 0.f, 0.f, 0.f};
    #pragma unroll
    for (int i = 0; i < 2; ++i)
        #pragma unroll
        for (int j = 0; j < 4; ++j) acc[i][j] = z;

    // staging sweep = 256 thr x 16B = 32 rows x 64 elems; wave w covers rows w*8..w*8+7.
    const int srow = tid >> 3;                          // 0..31 (row within sweep)
    const int schunk = ((tid & 7) ^ (srow & 7)) * 8;    // swizzled 8-elem chunk (phys for ds_write, logical for gl_lds)
    const bf16* pB0 = Bt + (size_t)(n0 + srow) * K + schunk;
    const bf16* pB1 = Bt + (size_t)(n0 + 32 + srow) * K + schunk;
    const bf16* pB2 = Bt + (size_t)(n0 + 64 + srow) * K + schunk;
    const bf16* pB3 = Bt + (size_t)(n0 + 96 + srow) * K + schunk;
    const bf16* pA0 = (EPI == 0) ? A + (size_t)(m0 + srow) * K + schunk : nullptr;
    const bf16* pA1 = (EPI == 0) ? A + (size_t)(m0 + 32 + srow) * K + schunk : nullptr;
    const int lw = w * 512;   // wave-uniform LDS offset within each 2048-elem sweep region

    const int NT = K >> 6;    // 16 K-steps

    // ---- prologue: stage tile 0 into buffer 0 ----
    if (EPI == 0) {
        gl_lds16(pA0, &As[0][lw]);
        gl_lds16(pA1, &As[0][2048 + lw]);
    } else {
        #pragma unroll
        for (int s = 0; s < 2; ++s) {
            const float* src = Af + (size_t)(m0 + s * 32 + srow) * K + (tid & 7) * 8;
            const float4 v0 = *(const float4*)src;
            const float4 v1 = *(const float4*)(src + 4);
            bf16x8 t8;
            t8[0] = (bf16)v0.x; t8[1] = (bf16)v0.y; t8[2] = (bf16)v0.z; t8[3] = (bf16)v0.w;
            t8[4] = (bf16)v1.x; t8[5] = (bf16)v1.y; t8[6] = (bf16)v1.z; t8[7] = (bf16)v1.w;
            *(bf16x8*)&As[0][(s * 32 + srow) * 64 + schunk] = t8;
        }
    }
    gl_lds16(pB0, &Bs[0][lw]);
    gl_lds16(pB1, &Bs[0][2048 + lw]);
    gl_lds16(pB2, &Bs[0][4096 + lw]);
    gl_lds16(pB3, &Bs[0][6144 + lw]);
    __syncthreads();

    for (int t = 0; t < NT; ++t) {
        const int cur = t & 1;
        const int kk = (t + 1) << 6;
        float4 va[2][2];
        // ---- issue next-tile staging FIRST (overlaps with compute below) ----
        if (t + 1 < NT) {
            if (EPI == 0) {
                gl_lds16(pA0 + kk, &As[cur ^ 1][lw]);
                gl_lds16(pA1 + kk, &As[cur ^ 1][2048 + lw]);
            } else {
                // T14 split: issue loads now, cvt+ds_write after the MFMA block
                #pragma unroll
                for (int s = 0; s < 2; ++s) {
                    const float* src = Af + (size_t)(m0 + s * 32 + srow) * K + kk + (tid & 7) * 8;
                    va[s][0] = *(const float4*)src;
                    va[s][1] = *(const float4*)(src + 4);
                }
            }
            gl_lds16(pB0 + kk, &Bs[cur ^ 1][lw]);
            gl_lds16(pB1 + kk, &Bs[cur ^ 1][2048 + lw]);
            gl_lds16(pB2 + kk, &Bs[cur ^ 1][4096 + lw]);
            gl_lds16(pB3 + kk, &Bs[cur ^ 1][6144 + lw]);
        }
        // ---- compute current tile ----
        #pragma unroll
        for (int tt = 0; tt < 2; ++tt) {
            const int phys = ((tt * 4 + g) ^ (li & 7)) * 8;
            bf16x8 af[2], bfr[4];
            #pragma unroll
            for (int mi = 0; mi < 2; ++mi) af[mi] = *(const bf16x8*)&As[cur][(wm * 32 + mi * 16 + li) * 64 + phys];
            #pragma unroll
            for (int ni = 0; ni < 4; ++ni) bfr[ni] = *(const bf16x8*)&Bs[cur][(wn * 64 + ni * 16 + li) * 64 + phys];
            #pragma unroll
            for (int mi = 0; mi < 2; ++mi)
                #pragma unroll
                for (int ni = 0; ni < 4; ++ni)
                    acc[mi][ni] = __builtin_amdgcn_mfma_f32_16x16x32_bf16(af[mi], bfr[ni], acc[mi][ni], 0, 0, 0);
        }
        // ---- late A-write for the fused-conversion path ----
        if (EPI == 2 && t + 1 < NT) {
            #pragma unroll
            for (int s = 0; s < 2; ++s) {
                bf16x8 t8;
                t8[0] = (bf16)va[s][0].x; t8[1] = (bf16)va[s][0].y; t8[2] = (bf16)va[s][0].z; t8[3] = (bf16)va[s][0].w;
                t8[4] = (bf16)va[s][1].x; t8[5] = (bf16)va[s][1].y; t8[6] = (bf16)va[s][1].z; t8[7] = (bf16)va[s][1].w;
                *(bf16x8*)&As[cur ^ 1][(s * 32 + srow) * 64 + schunk] = t8;
            }
        }
        __syncthreads();
    }

    const int row0 = m0 + wm * 32, col0 = n0 + wn * 64;
    if (EPI == 0) {
        #pragma unroll
        for (int mi = 0; mi < 2; ++mi)
            #pragma unroll
            for (int ni = 0; ni < 4; ++ni)
                #pragma unroll
                for (int r = 0; r < 4; ++r)
                    C[(size_t)(row0 + mi * 16 + g * 4 + r) * N + col0 + ni * 16 + li] = acc[mi][ni][r];
    } else {
        // fused RoPE + split. cols: [0,1024) q (pre-scaled), [1024,1280) k, [1280,1536) v.
        // rotate_half partner of col is col^32 == acc[mi][ni^2][r] (same wave, in-register).
        #pragma unroll
        for (int ni = 0; ni < 4; ++ni) {
            const int col = col0 + ni * 16 + li;
            const int d = col & 63;
            #pragma unroll
            for (int mi = 0; mi < 2; ++mi) {
                #pragma unroll
                for (int r = 0; r < 4; ++r) {
                    const int row = row0 + mi * 16 + g * 4 + r;
                    const int bb = row >> 11, s = row & 2047;
                    float val = acc[mi][ni][r];
                    if (col < 1280) {
                        const float pairv = acc[mi][ni ^ 2][r];
                        const float rot = (d < 32) ? -pairv : pairv;
                        val = val * cosp[s * 64 + d] + rot * sinp[s * 64 + d];
                    }
                    if (col < 1024) {
                        const int hh = col >> 6;
                        qo[(((size_t)bb * NH + hh) * SS + s) * HD + d] = (bf16)(val * SM_SCALE);
                    } else if (col < 1280) {
                        const int kh = (col - 1024) >> 6;
                        ko[(((size_t)bb * NKV + kh) * SS + s) * HD + d] = (bf16)val;
                    } else {
                        const int kh = (col - 1280) >> 6;
                        vto[(((size_t)bb * NKV + kh) * HD + d) * SS + s] = (bf16)val;  // V^T: [d][s]
                    }
                }
            }
        }
    }
}

// ---------------- Flash attention v8: swapped QK^T -> packed P writes ----------------
// 1024 blocks x 256 thr. qt = 31 - blk/32 (heaviest first), (b,h) = blk&31.
// Ks/Vt unpadded + chunk-XOR swizzle, staged via global_load_lds (8 calls / 128 keys).
// QK^T computed SWAPPED: s = mfma(kf, qf) so lane (li,g) holds S[key=nt*16+g*4+r][q=li]
// -> 4-consecutive-key runs of the lane's own q-row. exp2'd runs pack to bf16x4 and store
// with ONE ds_write_b64 per nt (was 16 scalar ds_write_b16 per sub-tile).
// Ps per wave = [q=16][key=64] bf16, 8B-chunk XOR swizzle: phys_chunk = c ^ ((li&7)<<1).
__global__ __launch_bounds__(256) void flash_kernel(const bf16* __restrict__ q, const bf16* __restrict__ k,
                                                    const bf16* __restrict__ vt, bf16* __restrict__ o)
{
    __shared__ bf16 Ks[128 * 64];    // 16 KB: 128 keys x 64 d, swizzled
    __shared__ bf16 Vt[64 * 128];    // 16 KB: 64 d x 128 keys, swizzled
    __shared__ bf16 Ps[4][16 * 64];  //  8 KB: per-wave P [q][key], chunk-swizzled

    const int blk = blockIdx.x;
    const int qt = 31 - (blk >> 5);          // heavy blocks dispatched first
    const int h = blk & 15;
    const int b = (blk >> 4) & 1;
    const int kvh = h >> 2;
    const int tid = threadIdx.x;
    const int w = tid >> 6, lane = tid & 63, g = lane >> 4, li = lane & 15;

    const bf16* qh = q + ((size_t)b * NH + h) * SS * HD;
    const bf16* kh = k + ((size_t)b * NKV + kvh) * SS * HD;
    const bf16* vh = vt + ((size_t)b * NKV + kvh) * (size_t)HD * SS;

    bf16x8 ones;
    #pragma unroll
    for (int j = 0; j < 8; ++j) ones[j] = (bf16)1.0f;
    const f32x4 z = {0.f, 0.f, 0.f, 0.f};

    // Q fragments straight from global (row=li, k=g*8+j); Q pre-scaled.
    const bf16* qrow = qh + (size_t)(qt * 64 + w * 16 + li) * HD;
    bf16x8 qf[2];
    qf[0] = *(const bf16x8*)(qrow + g * 8);
    qf[1] = *(const bf16x8*)(qrow + 32 + g * 8);

    // staging lane maps (swizzled, wave-uniform LDS dests)
    const int ksrow = tid >> 3;                              // K: 0..31 within 32-row sweep
    const int kchunk = ((tid & 7) ^ (ksrow & 7)) * 8;
    const int vsrow = tid >> 4;                              // Vt: 0..15 within 16-row sweep
    const int vchunk = (((tid & 15) ^ (vsrow & 7)) & 15) * 8;
    bf16* lK = Ks + (size_t)w * 512;
    bf16* lV = Vt + (size_t)w * 512;

    const int xm = (li & 7) << 1;   // even Ps chunk-XOR mask (row-dependent, read==write)

    f32x4 o_acc[4], l_acc;
    #pragma unroll
    for (int nt = 0; nt < 4; ++nt) o_acc[nt] = z;
    l_acc = z;

    for (int kt0 = 0; kt0 <= qt; kt0 += 2) {
        __syncthreads();
        {   // stage 128 keys of K (4 sweeps x 32 rows) and V^T (4 sweeps x 16 d-rows)
            #pragma unroll
            for (int s = 0; s < 4; ++s)
                gl_lds16(kh + (size_t)(kt0 * 64 + s * 32 + ksrow) * HD + kchunk, lK + s * 2048);
            #pragma unroll
            for (int s = 0; s < 4; ++s)
                gl_lds16(vh + (size_t)(s * 16 + vsrow) * SS + kt0 * 64 + vchunk, lV + s * 2048);
        }
        __syncthreads();

        #pragma unroll
        for (int sub = 0; sub < 2; ++sub) {
            const int kt = kt0 + sub;
            if (kt > qt) break;

            // S^T-fragment = K @ Q^T (swapped): lane (li,g) holds S[key=nt*16+g*4+r][q=li]
            f32x4 s_acc[4];
            #pragma unroll
            for (int nt = 0; nt < 4; ++nt) s_acc[nt] = z;
            #pragma unroll
            for (int t = 0; t < 2; ++t)
                #pragma unroll
                for (int nt = 0; nt < 4; ++nt) {
                    const bf16x8 kf = *(const bf16x8*)&Ks[(sub * 64 + nt * 16 + li) * 64 + (((t * 4 + g) ^ (li & 7)) * 8)];
                    s_acc[nt] = __builtin_amdgcn_mfma_f32_16x16x32_bf16(kf, qf[t], s_acc[nt], 0, 0, 0);
                }

            // exp2 + packed P -> LDS (bf16x4 per nt). Diag tile masked separately.
            if (kt == qt) {
                const int qrow_in = w * 16 + li;   // q within the 64-row q-tile
                #pragma unroll
                for (int nt = 0; nt < 4; ++nt) {
                    bf16x4 p4;
                    #pragma unroll
                    for (int r = 0; r < 4; ++r) {
                        float sv = s_acc[nt][r];
                        if (nt * 16 + g * 4 + r > qrow_in) sv = -1e30f;
                        p4[r] = (bf16)exp2f(sv);
                    }
                    *(bf16x4*)&Ps[w][li * 64 + (((nt * 4 + g) ^ xm) * 4)] = p4;
                }
            } else {
                #pragma unroll
                for (int nt = 0; nt < 4; ++nt) {
                    bf16x4 p4;
                    #pragma unroll
                    for (int r = 0; r < 4; ++r) p4[r] = (bf16)exp2f(s_acc[nt][r]);
                    *(bf16x4*)&Ps[w][li * 64 + (((nt * 4 + g) ^ xm) * 4)] = p4;
                }
            }
            // same-wave LDS round-trip (rows are the lane's own q=li); no barrier needed

            // O += P @ V ; l += P @ 1 (rowsum via ones-MFMA)
            #pragma unroll
            for (int t = 0; t < 2; ++t) {
                const bf16x8 pf = *(const bf16x8*)&Ps[w][li * 64 + (((t * 8 + g * 2) ^ xm) * 4)];
                l_acc = __builtin_amdgcn_mfma_f32_16x16x32_bf16(pf, ones, l_acc, 0, 0, 0);
                #pragma unroll
                for (int nt = 0; nt < 4; ++nt) {
                    const bf16x8 vf = *(const bf16x8*)&Vt[(nt * 16 + li) * 128 + (((sub * 8 + t * 4 + g) ^ (li & 7)) * 8)];
                    o_acc[nt] = __builtin_amdgcn_mfma_f32_16x16x32_bf16(pf, vf, o_acc[nt], 0, 0, 0);
                }
            }
        }
    }

    // epilogue: O / l -> (b, s, h, d) bf16
    #pragma unroll
    for (int r = 0; r < 4; ++r) {
        const float inv = 1.f / l_acc[r];
        const int s = qt * 64 + w * 16 + g * 4 + r;
        bf16* orow = o + (((size_t)b * SS + s) * NH + h) * HD;
        #pragma unroll
        for (int nt = 0; nt < 4; ++nt) orow[nt * 16 + li] = (bf16)(o_acc[nt][r] * inv);
    }
}

extern "C" void kernel_launch(void* const* d_in, const int* in_sizes, int n_in,
                              void* d_out, int out_size, void* d_ws, size_t ws_size,
                              hipStream_t stream) {
    const float* x     = (const float*)d_in[0];
    const float* cos_t = (const float*)d_in[1];
    const float* sin_t = (const float*)d_in[2];
    const float* Wq    = (const float*)d_in[3];
    const float* Wk    = (const float*)d_in[4];
    const float* Wv    = (const float*)d_in[5];
    const float* Wo    = (const float*)d_in[6];
    float* out = (float*)d_out;

    char* wsb = (char*)d_ws;
    bf16* o_b    = (bf16*)(wsb);                 //  8,388,608 B (attention output)
    bf16* wqkv_t = (bf16*)(wsb + 8388608);       //  3,145,728 B (1536 x 1024)
    bf16* wo_t   = (bf16*)(wsb + 11534336);      //  2,097,152 B (1024 x 1024)
    bf16* q_b    = (bf16*)(wsb + 13631488);      //  8,388,608 B
    bf16* k_b    = (bf16*)(wsb + 22020096);      //  2,097,152 B
    bf16* vt_b   = (bf16*)(wsb + 24117248);      //  2,097,152 B -> total 26,214,400 B

    prep_kernel<<<640, 256, 0, stream>>>(Wq, Wk, Wv, Wo, wqkv_t, wo_t);

    // QKV GEMM: A = x (fp32, converted in-staging) with fused RoPE + split, 64x128 tiles
    gemm_bt_kernel<2><<<dim3(64, 12), 256, 0, stream>>>(nullptr, x, wqkv_t, nullptr, cos_t, sin_t,
                                                        q_b, k_b, vt_b, 4096, 1536, 1024);
    flash_kernel<<<1024, 256, 0, stream>>>(q_b, k_b, vt_b, o_b);
    gemm_bt_kernel<0><<<dim3(64, 8), 256, 0, stream>>>(o_b, nullptr, wo_t, out, nullptr, nullptr,
                                                       nullptr, nullptr, nullptr, 4096, 1024, 1024);
}